// Round 7
// baseline (15.307 us; speedup 1.0000x reference)
//
#include <hip/hip_runtime.h>

constexpr int    NN     = 8192;
constexpr float  MARGIN = 0.01f;
constexpr int    BT     = 256;           // threads per block
constexpr int    FI     = 2;             // i-rows per thread
constexpr int    TI     = BT * FI;       // 512 i-rows per block
constexpr int    TJ     = 32;            // j-chunk per block
constexpr int    NTI    = NN / TI;       // 16
constexpr int    NTJ    = NN / TJ;       // 256
// row ib: jc in [16*ib, 256) -> (256 - 16*ib) chunks; total:
constexpr int    NBLOCKS = 16 * 256 - 16 * 120;   // 2176

// Symmetry: hinge(i,j)==hinge(j,i). For i-tile ib, chunks t<16 lie inside the
// 512x512 diagonal tile -> each ordered pair once, no doubling; t>=16 ->
// strictly upper tiles, doubled. i==j slots contribute exactly MARGIN each;
// subtracted analytically. count = NN*(NN-1) (continuous data, no off-diag
// ties; validated absmax==0 rounds 3-6).
__global__ __launch_bounds__(BT)
void pair_kernel(const float* __restrict__ pred,
                 const float* __restrict__ act,
                 const float* __restrict__ prev,
                 float* __restrict__ rank_part,    // [NBLOCKS]
                 float* __restrict__ price_part)   // [NTI]
{
    // decode flat block id -> (ib, t)
    int t  = blockIdx.x;
    int ib = 0;
    while (t >= NTJ - 16 * ib) { t -= NTJ - 16 * ib; ++ib; }
    const int  jc        = 16 * ib + t;
    const bool diag_like = (t < 16);
    const bool do_price  = (t == 0);

    __shared__ alignas(16) float2 s_t[TJ];
    __shared__ float s_red[BT];
    __shared__ float s_pp[BT];

    const int tid = threadIdx.x;
    if (tid < TJ) {
        const int   j   = jc * TJ + tid;
        const float pv  = prev[j];
        const float rcp = __builtin_amdgcn_rcpf(pv);
        s_t[tid] = make_float2((pred[j] - pv) * rcp, (act[j] - pv) * rcp);
    }

    // 2 i-rows per thread: ib*512 + tid + {0,256} (coalesced)
    float pri[FI], ari[FI];
    float pp = 0.f;
#pragma unroll
    for (int f = 0; f < FI; ++f) {
        const int   i   = ib * TI + f * BT + tid;
        const float pv  = prev[i];
        const float p   = pred[i];
        const float a   = act[i];
        const float rcp = __builtin_amdgcn_rcpf(pv);
        pri[f] = (p - pv) * rcp;
        ari[f] = (a - pv) * rcp;
        const float d = p - a;
        pp += d * d;
    }

    __syncthreads();

    float acc[4] = {0.f, 0.f, 0.f, 0.f};

#define PAIR(f, k, pj, aj)                                  \
    {                                                       \
        const float ad = ari[f] - (aj);                     \
        const float pd = pri[f] - (pj);                     \
        const float s  = (ad > 0.0f) ? -1.0f : 1.0f;        \
        acc[k] += fmaxf(0.0f, fmaf(s, pd, MARGIN));         \
    }

    const float4* __restrict__ s4 = (const float4*)s_t;   // 16 x (2 j's)
#pragma unroll
    for (int g = 0; g < TJ / 2; ++g) {
        const float4 q = s4[g];
        PAIR(0, 0, q.x, q.y); PAIR(1, 1, q.x, q.y);
        PAIR(0, 2, q.z, q.w); PAIR(1, 3, q.z, q.w);
    }
#undef PAIR

    float w = (acc[0] + acc[1]) + (acc[2] + acc[3]);
    if (!diag_like) w += w;                 // doubled tiles (exact in f32)

    s_red[tid] = w;
    s_pp[tid]  = pp;
    __syncthreads();

    if (tid < 64) {
        float r = s_red[tid] + s_red[tid + 64] + s_red[tid + 128] + s_red[tid + 192];
        for (int off = 32; off > 0; off >>= 1) r += __shfl_down(r, off, 64);
        if (tid == 0) rank_part[blockIdx.x] = r;
        if (do_price) {
            float q = s_pp[tid] + s_pp[tid + 64] + s_pp[tid + 128] + s_pp[tid + 192];
            for (int off = 32; off > 0; off >>= 1) q += __shfl_down(q, off, 64);
            if (tid == 0) price_part[ib] = q;
        }
    }
}

__global__ __launch_bounds__(256)
void finalize_kernel(const float* __restrict__ rank_part,
                     const float* __restrict__ price_part,
                     float* __restrict__ out)
{
    double s = 0.0, p = 0.0;
    for (int t = threadIdx.x; t < NBLOCKS; t += 256) s += (double)rank_part[t];
    if (threadIdx.x < NTI) p = (double)price_part[threadIdx.x];
    for (int off = 32; off > 0; off >>= 1) {
        s += __shfl_down(s, off, 64);
        p += __shfl_down(p, off, 64);
    }
    __shared__ double rs[4], rp[4];
    const int w = threadIdx.x >> 6;
    if ((threadIdx.x & 63) == 0) { rs[w] = s; rp[w] = p; }
    __syncthreads();
    if (threadIdx.x == 0) {
        const double S = rs[0] + rs[1] + rs[2] + rs[3];
        const double P = rp[0] + rp[1] + rp[2] + rp[3];
        const double rank = (S - (double)NN * (double)MARGIN)
                          / ((double)NN * (double)(NN - 1));
        out[0] = (float)(0.5 * (P / (double)NN) + 0.5 * rank);
    }
}

extern "C" void kernel_launch(void* const* d_in, const int* in_sizes, int n_in,
                              void* d_out, int out_size, void* d_ws, size_t ws_size,
                              hipStream_t stream)
{
    const float* pred = (const float*)d_in[0];
    const float* act  = (const float*)d_in[1];
    const float* prev = (const float*)d_in[2];

    char* w = (char*)d_ws;
    float* rank_part  = (float*)w;              // 2176 * 4 B
    float* price_part = (float*)(w + 12288);    // 16 * 4 B

    pair_kernel<<<NBLOCKS, BT, 0, stream>>>(pred, act, prev, rank_part, price_part);
    finalize_kernel<<<1, 256, 0, stream>>>(rank_part, price_part, (float*)d_out);
}